// Round 2
// baseline (11.744 us; speedup 1.0000x reference)
//
#include <hip/hip_runtime.h>

#define NCH     262144
#define BUF_LEN 201
#define NP      9
#define DT      0.001f
#define CHANGE_EPS 1e-4f

__global__ __launch_bounds__(256) void pam_delay_kernel(
    const float* __restrict__ target,
    const float* __restrict__ current,
    const float* __restrict__ prev_target,
    const float* __restrict__ p_start_latch,
    const float* __restrict__ p_axis,
    const float* __restrict__ tau_table,
    const float* __restrict__ dead_table,
    const float* __restrict__ delay_buf,
    const int*   __restrict__ write_idx_p,
    float* __restrict__ out,
    int n)
{
    // Stage tiny LUTs in LDS: axis (9) + tau (81) + dead (81)
    __shared__ float s_axis[NP];
    __shared__ float s_tau[NP * NP];
    __shared__ float s_dead[NP * NP];
    {
        int t = threadIdx.x;
        if (t < NP) s_axis[t] = p_axis[t];
        for (int i = t; i < NP * NP; i += blockDim.x) {
            s_tau[i]  = tau_table[i];
            s_dead[i] = dead_table[i];
        }
    }
    __syncthreads();

    int gid = blockIdx.x * blockDim.x + threadIdx.x;
    if (gid >= n) return;

    float tgt = target[gid];
    float cur = current[gid];
    float prv = prev_target[gid];
    float lat = p_start_latch[gid];

    // 1) masked latch of start pressure on target change
    bool change = fabsf(tgt - prv) > CHANGE_EPS;
    float pst = change ? cur : lat;

    // 2) bilinear LUT lookup (shared indices/weights for both tables)
    float lo = s_axis[0], hi = s_axis[NP - 1];
    float xq = fminf(fmaxf(tgt, lo), hi);
    float yq = fminf(fmaxf(pst, lo), hi);

    // searchsorted(axis, q, 'right') - 1, clipped to [0, NP-2]
    int ix = 0, iy = 0;
#pragma unroll
    for (int j = 1; j <= NP - 2; ++j) {
        if (xq >= s_axis[j]) ix = j;
        if (yq >= s_axis[j]) iy = j;
    }
    float x0 = s_axis[ix],  x1 = s_axis[ix + 1];
    float y0a = s_axis[iy], y1a = s_axis[iy + 1];
    float tx = (xq - x0) / (x1 - x0);
    float ty = (yq - y0a) / (y1a - y0a);

    float w00 = (1.0f - tx) * (1.0f - ty);
    float w10 = tx * (1.0f - ty);
    float w01 = (1.0f - tx) * ty;
    float w11 = tx * ty;

    int b = ix * NP + iy;   // table[ix][iy]; +NP -> ix+1, +1 -> iy+1
    float tau = w00 * s_tau[b]      + w10 * s_tau[b + NP]
              + w01 * s_tau[b + 1]  + w11 * s_tau[b + NP + 1];
    float L   = w00 * s_dead[b]     + w10 * s_dead[b + NP]
              + w01 * s_dead[b + 1] + w11 * s_dead[b + NP + 1];

    // 3) fractional delay read (virtual write of tgt at write_idx)
    int widx = *write_idx_p;
    float d = fminf(fmaxf(L / DT, 0.0f), (float)(BUF_LEN - 1));
    int   i0   = (int)floorf(d);
    float frac = d - (float)i0;

    int p0 = widx - i0;
    p0 %= BUF_LEN; if (p0 < 0) p0 += BUF_LEN;
    int p1 = p0 - 1; if (p1 < 0) p1 += BUF_LEN;

    const float* row = delay_buf + (size_t)gid * BUF_LEN;
    float v0 = (p0 == widx) ? tgt : row[p0];
    float v1 = (p1 == widx) ? tgt : row[p1];
    float p_delayed = (1.0f - frac) * v0 + frac * v1;

    // 4) first-order lag
    float alpha = 1.0f - expf(-DT / tau);
    out[gid] = cur + alpha * (p_delayed - cur);
}

extern "C" void kernel_launch(void* const* d_in, const int* in_sizes, int n_in,
                              void* d_out, int out_size, void* d_ws, size_t ws_size,
                              hipStream_t stream) {
    const float* target        = (const float*)d_in[0];
    const float* current       = (const float*)d_in[1];
    const float* prev_target   = (const float*)d_in[2];
    const float* p_start_latch = (const float*)d_in[3];
    const float* p_axis        = (const float*)d_in[4];
    const float* tau_table     = (const float*)d_in[5];
    const float* dead_table    = (const float*)d_in[6];
    const float* delay_buf     = (const float*)d_in[7];
    const int*   write_idx     = (const int*)d_in[8];
    float* out = (float*)d_out;

    int n = in_sizes[0];
    int block = 256;
    int grid = (n + block - 1) / block;
    pam_delay_kernel<<<grid, block, 0, stream>>>(
        target, current, prev_target, p_start_latch,
        p_axis, tau_table, dead_table, delay_buf, write_idx, out, n);
}